// Round 1
// baseline (4953.525 us; speedup 1.0000x reference)
//
#include <hip/hip_runtime.h>

#define NN 100000
#define NE 1600000
#define DIN 128
#define HH 64
#define NG 512

// ---------------- degree ----------------
__global__ void k_deg(const int* __restrict__ dst, float* __restrict__ deg) {
    int e = blockIdx.x * blockDim.x + threadIdx.x;
    if (e < NE) atomicAdd(&deg[dst[e]], 1.0f);
}

__global__ void k_inv(float* deg) {
    int n = blockIdx.x * blockDim.x + threadIdx.x;
    if (n < NN) deg[n] = 1.0f / fmaxf(deg[n], 1.0f);
}

// ---------------- input GEMM: h = relu(x @ W0 + b0) ----------------
// wave per row, lane = output column j; W0 [128,64] staged in LDS (32 KB)
__global__ void __launch_bounds__(256) k_in_gemm(const float* __restrict__ x,
                                                 const float* __restrict__ W0,
                                                 const float* __restrict__ b0,
                                                 float* __restrict__ h) {
    __shared__ float sW[DIN * 64];
    for (int i = threadIdx.x; i < DIN * 64; i += 256) sW[i] = W0[i];
    __syncthreads();
    int lane = threadIdx.x & 63;
    int wid  = (blockIdx.x * 256 + threadIdx.x) >> 6;
    int nw   = (gridDim.x * 256) >> 6;
    float bj = b0[lane];
    for (int n = wid; n < NN; n += nw) {
        const float* xr = x + (size_t)n * DIN;
        float acc = bj;
#pragma unroll 8
        for (int k = 0; k < DIN; ++k)
            acc = fmaf(xr[k], sW[k * 64 + lane], acc);
        h[(size_t)n * 64 + lane] = fmaxf(acc, 0.0f);
    }
}

// ---------------- edge scatter: agg[dst] += h[src] ----------------
// 16 threads per edge, float4 load, 4 scalar atomics each
__global__ void k_scatter(const int* __restrict__ src, const int* __restrict__ dst,
                          const float4* __restrict__ h4, float* __restrict__ agg) {
    int gid = blockIdx.x * blockDim.x + threadIdx.x;
    int e = gid >> 4;
    if (e >= NE) return;
    int q = gid & 15;
    int s = src[e];
    int d = dst[e];
    float4 v = h4[(size_t)s * 16 + q];
    float* p = agg + (size_t)d * 64 + q * 4;
    atomicAdd(p + 0, v.x);
    atomicAdd(p + 1, v.y);
    atomicAdd(p + 2, v.z);
    atomicAdd(p + 3, v.w);
}

// ---------------- layer transform: agg <- relu((agg*inv)@Wl + bl + h@Wr) ----------------
// wave per row; reads full agg row & h row, writes agg row in place (safe: write after loop)
__global__ void __launch_bounds__(256) k_layer(const float* __restrict__ hin,
                                               float* __restrict__ agg,
                                               const float* __restrict__ inv_deg,
                                               const float* __restrict__ Wl,
                                               const float* __restrict__ bl,
                                               const float* __restrict__ Wr) {
    __shared__ float sWl[64 * 64];
    __shared__ float sWr[64 * 64];
    for (int i = threadIdx.x; i < 64 * 64; i += 256) {
        sWl[i] = Wl[i];
        sWr[i] = Wr[i];
    }
    __syncthreads();
    int lane = threadIdx.x & 63;
    int wid  = (blockIdx.x * 256 + threadIdx.x) >> 6;
    int nw   = (gridDim.x * 256) >> 6;
    float bj = bl[lane];
    for (int n = wid; n < NN; n += nw) {
        const float* ar = agg + (size_t)n * 64;
        const float* hr = hin + (size_t)n * 64;
        float accL = 0.0f, accR = 0.0f;
#pragma unroll 8
        for (int k = 0; k < 64; ++k) {
            accL = fmaf(ar[k], sWl[k * 64 + lane], accL);
            accR = fmaf(hr[k], sWr[k * 64 + lane], accR);
        }
        float inv = inv_deg[n];
        float v = fmaxf(fmaf(accL, inv, bj) + accR, 0.0f);
        agg[(size_t)n * 64 + lane] = v;
    }
}

// ---------------- pooling ----------------
__global__ void k_cnt(const int* __restrict__ batch, float* __restrict__ cnt) {
    int n = blockIdx.x * blockDim.x + threadIdx.x;
    if (n < NN) atomicAdd(&cnt[batch[n]], 1.0f);
}

__global__ void k_pool(const int* __restrict__ batch, const float4* __restrict__ h4,
                       float* __restrict__ pool) {
    int gid = blockIdx.x * blockDim.x + threadIdx.x;
    int n = gid >> 4;
    if (n >= NN) return;
    int q = gid & 15;
    int g = batch[n];
    float4 v = h4[(size_t)n * 16 + q];
    float* p = pool + (size_t)g * 64 + q * 4;
    atomicAdd(p + 0, v.x);
    atomicAdd(p + 1, v.y);
    atomicAdd(p + 2, v.z);
    atomicAdd(p + 3, v.w);
}

// ---------------- output GEMM: out = (pool/cnt) @ W1 + b1 ----------------
__global__ void __launch_bounds__(256) k_out(const float* __restrict__ pool,
                                             const float* __restrict__ cnt,
                                             const float* __restrict__ W1,
                                             const float* __restrict__ b1,
                                             float* __restrict__ out) {
    __shared__ float sW[64 * 64];
    for (int i = threadIdx.x; i < 64 * 64; i += 256) sW[i] = W1[i];
    __syncthreads();
    int lane = threadIdx.x & 63;
    int wid  = (blockIdx.x * 256 + threadIdx.x) >> 6;
    int nw   = (gridDim.x * 256) >> 6;
    for (int g = wid; g < NG; g += nw) {
        float ic = 1.0f / fmaxf(cnt[g], 1.0f);
        float acc = 0.0f;
#pragma unroll 8
        for (int k = 0; k < 64; ++k)
            acc = fmaf(pool[(size_t)g * 64 + k], sW[k * 64 + lane], acc);
        out[(size_t)g * 64 + lane] = fmaf(acc, ic, b1[lane]);
    }
}

extern "C" void kernel_launch(void* const* d_in, const int* in_sizes, int n_in,
                              void* d_out, int out_size, void* d_ws, size_t ws_size,
                              hipStream_t stream) {
    const float* x     = (const float*)d_in[0];
    const int*   ei    = (const int*)d_in[1];   // [2,E]: src = ei[0..E), dst = ei[E..2E)
    // d_in[2] = edge_attr, unused
    const int*   batch = (const int*)d_in[3];
    const float* W0    = (const float*)d_in[4];
    const float* b0    = (const float*)d_in[5];
    const float* Wl    = (const float*)d_in[6]; // [3,64,64]
    const float* bl    = (const float*)d_in[7]; // [3,64]
    const float* Wr    = (const float*)d_in[8]; // [3,64,64]
    const float* W1    = (const float*)d_in[9];
    const float* b1    = (const float*)d_in[10];
    float* out = (float*)d_out;

    char* ws = (char*)d_ws;
    size_t off = 0;
    auto alloc = [&](size_t bytes) -> void* {
        void* p = ws + off;
        off += (bytes + 255) & ~(size_t)255;
        return p;
    };
    float* A    = (float*)alloc((size_t)NN * 64 * 4);  // node features (ping)
    float* B    = (float*)alloc((size_t)NN * 64 * 4);  // node features (pong) / agg
    float* deg  = (float*)alloc((size_t)NN * 4);       // in-degree -> inv_deg (in place)
    float* pool = (float*)alloc((size_t)NG * 64 * 4);
    float* cnt  = (float*)alloc((size_t)NG * 4);

    const int* src = ei;
    const int* dst = ei + NE;

    // degree + inverse
    hipMemsetAsync(deg, 0, (size_t)NN * 4, stream);
    k_deg<<<(NE + 255) / 256, 256, 0, stream>>>(dst, deg);
    k_inv<<<(NN + 255) / 256, 256, 0, stream>>>(deg);

    // input projection
    k_in_gemm<<<1024, 256, 0, stream>>>(x, W0, b0, A);

    // 3 SAGE layers
    for (int l = 0; l < 3; ++l) {
        hipMemsetAsync(B, 0, (size_t)NN * 64 * 4, stream);
        k_scatter<<<(NE * 16 + 255) / 256, 256, 0, stream>>>(src, dst, (const float4*)A, B);
        k_layer<<<1024, 256, 0, stream>>>(A, B, deg, Wl + (size_t)l * 64 * 64,
                                          bl + (size_t)l * 64, Wr + (size_t)l * 64 * 64);
        float* t = A; A = B; B = t;  // new h now in A
    }

    // global mean pool + output GEMM
    hipMemsetAsync(pool, 0, (size_t)NG * 64 * 4, stream);
    hipMemsetAsync(cnt, 0, (size_t)NG * 4, stream);
    k_cnt<<<(NN + 255) / 256, 256, 0, stream>>>(batch, cnt);
    k_pool<<<(NN * 16 + 255) / 256, 256, 0, stream>>>(batch, (const float4*)A, pool);
    k_out<<<128, 256, 0, stream>>>(pool, cnt, W1, b1, out);
}

// Round 2
// 956.628 us; speedup vs baseline: 5.1781x; 5.1781x over previous
//
#include <hip/hip_runtime.h>

#define NN 100000
#define NE 1600000
#define DIN 128
#define HH 64
#define NG 512

// ---------------- degree (int) ----------------
__global__ void k_deg(const int* __restrict__ dst, int* __restrict__ degi) {
    int e = blockIdx.x * blockDim.x + threadIdx.x;
    if (e < NE) atomicAdd(&degi[dst[e]], 1);
}

// ---------------- single-block exclusive scan of degi -> rowptr ----------------
__global__ void __launch_bounds__(1024) k_scan(const int* __restrict__ degi,
                                               int* __restrict__ rowptr) {
    __shared__ int wsum[16];
    __shared__ int carry;
    if (threadIdx.x == 0) carry = 0;
    __syncthreads();
    int lane = threadIdx.x & 63;
    int w    = threadIdx.x >> 6;
    for (int base = 0; base < NN; base += 1024) {
        int i = base + (int)threadIdx.x;
        int v = (i < NN) ? degi[i] : 0;
        int s = v;
#pragma unroll
        for (int off = 1; off < 64; off <<= 1) {
            int t = __shfl_up(s, off);
            if (lane >= off) s += t;
        }
        if (lane == 63) wsum[w] = s;
        __syncthreads();
        if (w == 0 && lane < 16) {
            int ws = wsum[lane];
#pragma unroll
            for (int off = 1; off < 16; off <<= 1) {
                int t = __shfl_up(ws, off);
                if (lane >= off) ws += t;
            }
            wsum[lane] = ws;
        }
        __syncthreads();
        int excl = carry + (w > 0 ? wsum[w - 1] : 0) + (s - v);
        if (i < NN) rowptr[i] = excl;
        __syncthreads();
        if (threadIdx.x == 0) carry += wsum[15];
        __syncthreads();
    }
}

// ---------------- CSR fill: col[rowptr[d] + cursor[d]++] = src ----------------
__global__ void k_fill(const int* __restrict__ src, const int* __restrict__ dst,
                       const int* __restrict__ rowptr, int* __restrict__ cursor,
                       int* __restrict__ col) {
    int e = blockIdx.x * blockDim.x + threadIdx.x;
    if (e >= NE) return;
    int d   = dst[e];
    int pos = atomicAdd(&cursor[d], 1);
    col[rowptr[d] + pos] = src[e];
}

// ---------------- input GEMM: h = relu(x @ W0 + b0) ----------------
__global__ void __launch_bounds__(256) k_in_gemm(const float* __restrict__ x,
                                                 const float* __restrict__ W0,
                                                 const float* __restrict__ b0,
                                                 float* __restrict__ h) {
    __shared__ float sW[DIN * 64];
    for (int i = threadIdx.x; i < DIN * 64; i += 256) sW[i] = W0[i];
    __syncthreads();
    int lane = threadIdx.x & 63;
    int wid  = (blockIdx.x * 256 + threadIdx.x) >> 6;
    int nw   = (gridDim.x * 256) >> 6;
    float bj = b0[lane];
    for (int n = wid; n < NN; n += nw) {
        int nu = __builtin_amdgcn_readfirstlane(n);   // wave-uniform hint
        const float* xr = x + (size_t)nu * DIN;
        float acc = bj;
#pragma unroll 16
        for (int k = 0; k < DIN; ++k)
            acc = fmaf(xr[k], sW[k * 64 + lane], acc);
        h[(size_t)n * 64 + lane] = fmaxf(acc, 0.0f);
    }
}

// ---------------- fused SAGE layer: hout = relu(gather_mean(hin)@Wl + bl + hin@Wr) ----
// wave per node; lane = feature. CSR gather with register accumulation,
// agg row broadcast via per-wave LDS slot (wave-synchronous, no block barrier).
__global__ void __launch_bounds__(256) k_sage(const float* __restrict__ hin,
                                              float* __restrict__ hout,
                                              const int* __restrict__ rowptr,
                                              const int* __restrict__ degi,
                                              const int* __restrict__ col,
                                              const float* __restrict__ Wl,
                                              const float* __restrict__ bl,
                                              const float* __restrict__ Wr) {
    __shared__ float sWl[64 * 64];
    __shared__ float sWr[64 * 64];
    __shared__ float sbuf[4][64];
    for (int i = threadIdx.x; i < 64 * 64; i += 256) {
        sWl[i] = Wl[i];
        sWr[i] = Wr[i];
    }
    __syncthreads();
    int lane = threadIdx.x & 63;
    int w    = threadIdx.x >> 6;
    int wid  = (blockIdx.x << 2) + w;
    int nw   = gridDim.x << 2;
    float bj = bl[lane];
    for (int n = wid; n < NN; n += nw) {
        int start = rowptr[n];
        int dg    = degi[n];
        // ---- gather-sum neighbor rows ----
        float a0 = 0.0f, a1 = 0.0f;
        for (int t0 = 0; t0 < dg; t0 += 64) {
            int cnt   = min(dg - t0, 64);
            int myidx = (lane < cnt) ? col[start + t0 + lane] : 0;
            int t = 0;
            for (; t + 1 < cnt; t += 2) {
                int s0 = __shfl(myidx, t);
                int s1 = __shfl(myidx, t + 1);
                a0 += hin[(size_t)s0 * 64 + lane];
                a1 += hin[(size_t)s1 * 64 + lane];
            }
            if (t < cnt) {
                int s0 = __shfl(myidx, t);
                a0 += hin[(size_t)s0 * 64 + lane];
            }
        }
        float inv  = 1.0f / fmaxf((float)dg, 1.0f);
        float aggv = (a0 + a1) * inv;
        // ---- exchange agg row through per-wave LDS slot ----
        sbuf[w][lane] = aggv;
        __builtin_amdgcn_wave_barrier();
        int nu = __builtin_amdgcn_readfirstlane(n);
        const float* hr = hin + (size_t)nu * 64;
        float accL = bj, accR = 0.0f;
#pragma unroll
        for (int k = 0; k < 64; ++k) {
            accL = fmaf(sbuf[w][k], sWl[k * 64 + lane], accL);
            accR = fmaf(hr[k],      sWr[k * 64 + lane], accR);
        }
        __builtin_amdgcn_wave_barrier();
        hout[(size_t)n * 64 + lane] = fmaxf(accL + accR, 0.0f);
    }
}

// ---------------- pooling: batch is sorted -> run-accumulate, flush on change ----
__global__ void __launch_bounds__(256) k_pool(const int* __restrict__ batch,
                                              const float* __restrict__ h,
                                              float* __restrict__ pool,
                                              float* __restrict__ cnt) {
    int lane = threadIdx.x & 63;
    int wid  = (blockIdx.x * 256 + threadIdx.x) >> 6;
    int nw   = (gridDim.x * 256) >> 6;
    int chunk = (NN + nw - 1) / nw;
    int n0 = wid * chunk;
    if (n0 >= NN) return;
    int n1 = min(n0 + chunk, NN);
    int cur = batch[n0];
    float acc = 0.0f;
    float acc_c = 0.0f;
    for (int n = n0; n < n1; ++n) {
        int b = batch[n];
        if (b != cur) {
            atomicAdd(&pool[(size_t)cur * 64 + lane], acc);
            if (lane == 0) atomicAdd(&cnt[cur], acc_c);
            acc = 0.0f; acc_c = 0.0f; cur = b;
        }
        acc   += h[(size_t)n * 64 + lane];
        acc_c += 1.0f;
    }
    atomicAdd(&pool[(size_t)cur * 64 + lane], acc);
    if (lane == 0) atomicAdd(&cnt[cur], acc_c);
}

// ---------------- output GEMM: out = (pool/cnt) @ W1 + b1 ----------------
__global__ void __launch_bounds__(256) k_out(const float* __restrict__ pool,
                                             const float* __restrict__ cnt,
                                             const float* __restrict__ W1,
                                             const float* __restrict__ b1,
                                             float* __restrict__ out) {
    __shared__ float sW[64 * 64];
    for (int i = threadIdx.x; i < 64 * 64; i += 256) sW[i] = W1[i];
    __syncthreads();
    int lane = threadIdx.x & 63;
    int wid  = (blockIdx.x * 256 + threadIdx.x) >> 6;
    int nw   = (gridDim.x * 256) >> 6;
    for (int g = wid; g < NG; g += nw) {
        float ic = 1.0f / fmaxf(cnt[g], 1.0f);
        float acc = 0.0f;
#pragma unroll
        for (int k = 0; k < 64; ++k)
            acc = fmaf(pool[(size_t)g * 64 + k], sW[k * 64 + lane], acc);
        out[(size_t)g * 64 + lane] = fmaf(acc, ic, b1[lane]);
    }
}

extern "C" void kernel_launch(void* const* d_in, const int* in_sizes, int n_in,
                              void* d_out, int out_size, void* d_ws, size_t ws_size,
                              hipStream_t stream) {
    const float* x     = (const float*)d_in[0];
    const int*   ei    = (const int*)d_in[1];   // [2,E]: src = ei[0..E), dst = ei[E..2E)
    const int*   batch = (const int*)d_in[3];
    const float* W0    = (const float*)d_in[4];
    const float* b0    = (const float*)d_in[5];
    const float* Wl    = (const float*)d_in[6]; // [3,64,64]
    const float* bl    = (const float*)d_in[7]; // [3,64]
    const float* Wr    = (const float*)d_in[8]; // [3,64,64]
    const float* W1    = (const float*)d_in[9];
    const float* b1    = (const float*)d_in[10];
    float* out = (float*)d_out;

    char* ws = (char*)d_ws;
    size_t off = 0;
    auto alloc = [&](size_t bytes) -> void* {
        void* p = ws + off;
        off += (bytes + 255) & ~(size_t)255;
        return p;
    };
    float* A      = (float*)alloc((size_t)NN * 64 * 4);  // node features (ping)
    float* B      = (float*)alloc((size_t)NN * 64 * 4);  // node features (pong)
    int*   degi   = (int*)alloc((size_t)NN * 4);
    int*   rowptr = (int*)alloc((size_t)NN * 4);
    int*   cursor = (int*)alloc((size_t)NN * 4);
    int*   col    = (int*)alloc((size_t)NE * 4);
    float* pool   = (float*)alloc((size_t)NG * 64 * 4);
    float* cnt    = (float*)alloc((size_t)NG * 4);

    const int* src = ei;
    const int* dst = ei + NE;

    // ---- CSR build (once) ----
    hipMemsetAsync(degi,   0, (size_t)NN * 4, stream);
    hipMemsetAsync(cursor, 0, (size_t)NN * 4, stream);
    k_deg<<<(NE + 255) / 256, 256, 0, stream>>>(dst, degi);
    k_scan<<<1, 1024, 0, stream>>>(degi, rowptr);
    k_fill<<<(NE + 255) / 256, 256, 0, stream>>>(src, dst, rowptr, cursor, col);

    // ---- input projection ----
    k_in_gemm<<<1024, 256, 0, stream>>>(x, W0, b0, A);

    // ---- 3 fused SAGE layers (gather + transform) ----
    for (int l = 0; l < 3; ++l) {
        k_sage<<<1024, 256, 0, stream>>>(A, B, rowptr, degi, col,
                                         Wl + (size_t)l * 64 * 64,
                                         bl + (size_t)l * 64,
                                         Wr + (size_t)l * 64 * 64);
        float* t = A; A = B; B = t;  // new h now in A
    }

    // ---- global mean pool + output GEMM ----
    hipMemsetAsync(pool, 0, (size_t)NG * 64 * 4, stream);
    hipMemsetAsync(cnt,  0, (size_t)NG * 4, stream);
    k_pool<<<256, 256, 0, stream>>>(batch, A, pool, cnt);
    k_out<<<128, 256, 0, stream>>>(pool, cnt, W1, b1, out);
}

// Round 3
// 609.330 us; speedup vs baseline: 8.1295x; 1.5700x over previous
//
#include <hip/hip_runtime.h>

#define NN 100000
#define NE 1600000
#define DIN 128
#define HH 64
#define NG 512
#define SCAN_NB ((NN + 1023) / 1024)

// ---------------- degree (int), 4 edges/thread ----------------
__global__ void k_deg(const int4* __restrict__ dst4, int* __restrict__ degi) {
    int e4 = blockIdx.x * blockDim.x + threadIdx.x;
    if (e4 >= NE / 4) return;
    int4 d = dst4[e4];
    atomicAdd(&degi[d.x], 1);
    atomicAdd(&degi[d.y], 1);
    atomicAdd(&degi[d.z], 1);
    atomicAdd(&degi[d.w], 1);
}

// ---------------- scan pass 1: block-local exclusive scan + block sums ----------------
__global__ void __launch_bounds__(1024) k_scan1(const int* __restrict__ degi,
                                                int* __restrict__ rowptr,
                                                int* __restrict__ bsum) {
    __shared__ int wsum[16];
    int i    = blockIdx.x * 1024 + threadIdx.x;
    int lane = threadIdx.x & 63;
    int w    = threadIdx.x >> 6;
    int v = (i < NN) ? degi[i] : 0;
    int s = v;
#pragma unroll
    for (int off = 1; off < 64; off <<= 1) {
        int t = __shfl_up(s, off);
        if (lane >= off) s += t;
    }
    if (lane == 63) wsum[w] = s;
    __syncthreads();
    if (threadIdx.x < 16) {
        int ws = wsum[threadIdx.x];
#pragma unroll
        for (int off = 1; off < 16; off <<= 1) {
            int t = __shfl_up(ws, off);
            if ((int)threadIdx.x >= off) ws += t;
        }
        wsum[threadIdx.x] = ws;
        if (threadIdx.x == 15) bsum[blockIdx.x] = ws;
    }
    __syncthreads();
    int excl = (w > 0 ? wsum[w - 1] : 0) + (s - v);
    if (i < NN) rowptr[i] = excl;
}

// ---------------- scan pass 2: add block offsets; also init cursor ----------------
__global__ void __launch_bounds__(1024) k_scan2(int* __restrict__ rowptr,
                                                int* __restrict__ cursor,
                                                const int* __restrict__ bsum) {
    __shared__ int soff;
    if (threadIdx.x < 64) {
        int b   = blockIdx.x;
        int acc = 0;
        for (int j = threadIdx.x; j < b; j += 64) acc += bsum[j];
#pragma unroll
        for (int off = 32; off > 0; off >>= 1) acc += __shfl_down(acc, off);
        if (threadIdx.x == 0) soff = acc;
    }
    __syncthreads();
    int i = blockIdx.x * 1024 + threadIdx.x;
    if (i < NN) {
        int r = rowptr[i] + soff;
        rowptr[i] = r;
        cursor[i] = r;
    }
}

// ---------------- CSR fill: col[cursor[d]++] = src, 4 edges/thread ----------------
__global__ void k_fill(const int4* __restrict__ src4, const int4* __restrict__ dst4,
                       int* __restrict__ cursor, int* __restrict__ col) {
    int e4 = blockIdx.x * blockDim.x + threadIdx.x;
    if (e4 >= NE / 4) return;
    int4 s = src4[e4];
    int4 d = dst4[e4];
    col[atomicAdd(&cursor[d.x], 1)] = s.x;
    col[atomicAdd(&cursor[d.y], 1)] = s.y;
    col[atomicAdd(&cursor[d.z], 1)] = s.z;
    col[atomicAdd(&cursor[d.w], 1)] = s.w;
}

// ---------------- input GEMM: h = relu(x @ W0 + b0), 2 nodes/wave ----------------
__global__ void __launch_bounds__(512) k_in_gemm(const float* __restrict__ x,
                                                 const float* __restrict__ W0,
                                                 const float* __restrict__ b0,
                                                 float* __restrict__ h) {
    __shared__ float sW[DIN * 64];
    for (int i = threadIdx.x; i < DIN * 64; i += 512) sW[i] = W0[i];
    __syncthreads();
    int lane = threadIdx.x & 63;
    int wid  = __builtin_amdgcn_readfirstlane((blockIdx.x * 512 + threadIdx.x) >> 6);
    int nw   = (gridDim.x * 512) >> 6;
    float bj = b0[lane];
    for (int p = wid; p < NN / 2; p += nw) {
        int n0 = 2 * p, n1 = n0 + 1;
        const float* x0 = x + (size_t)n0 * DIN;
        const float* x1 = x + (size_t)n1 * DIN;
        float acc0 = bj, acc1 = bj;
#pragma unroll 16
        for (int k = 0; k < DIN; ++k) {
            float wv = sW[k * 64 + lane];
            acc0 = fmaf(x0[k], wv, acc0);
            acc1 = fmaf(x1[k], wv, acc1);
        }
        h[(size_t)n0 * 64 + lane] = fmaxf(acc0, 0.0f);
        h[(size_t)n1 * 64 + lane] = fmaxf(acc1, 0.0f);
    }
}

// ---------------- fused SAGE layer, 2 nodes/wave, scalarized gather ----------------
__global__ void __launch_bounds__(512) k_sage(const float* __restrict__ hin,
                                              float* __restrict__ hout,
                                              const int* __restrict__ rowptr,
                                              const int* __restrict__ degi,
                                              const int* __restrict__ col,
                                              const float* __restrict__ Wl,
                                              const float* __restrict__ bl,
                                              const float* __restrict__ Wr) {
    __shared__ float sWl[64 * 64];
    __shared__ float sWr[64 * 64];
    __shared__ float sb[8][2][64];
    for (int i = threadIdx.x; i < 64 * 64; i += 512) {
        sWl[i] = Wl[i];
        sWr[i] = Wr[i];
    }
    __syncthreads();
    int lane = threadIdx.x & 63;
    int w    = threadIdx.x >> 6;
    int wid  = __builtin_amdgcn_readfirstlane((blockIdx.x * 512 + threadIdx.x) >> 6);
    int nw   = (gridDim.x * 512) >> 6;
    float bj = bl[lane];

    auto gather = [&](int start, int dg) -> float {
        const int* cp = col + start;   // wave-uniform pointer -> scalar loads
        float a0 = 0.0f, a1 = 0.0f, a2 = 0.0f, a3 = 0.0f;
        int t = 0;
        for (; t + 4 <= dg; t += 4) {
            int s0 = cp[t], s1 = cp[t + 1], s2 = cp[t + 2], s3 = cp[t + 3];
            a0 += hin[(size_t)s0 * 64 + lane];
            a1 += hin[(size_t)s1 * 64 + lane];
            a2 += hin[(size_t)s2 * 64 + lane];
            a3 += hin[(size_t)s3 * 64 + lane];
        }
        for (; t < dg; ++t) a0 += hin[(size_t)cp[t] * 64 + lane];
        return (a0 + a1) + (a2 + a3);
    };

    for (int p = wid; p < NN / 2; p += nw) {
        int n0 = 2 * p, n1 = n0 + 1;
        int st0 = rowptr[n0], dg0 = degi[n0];
        int st1 = rowptr[n1], dg1 = degi[n1];
        float agg0 = gather(st0, dg0) * (1.0f / fmaxf((float)dg0, 1.0f));
        float agg1 = gather(st1, dg1) * (1.0f / fmaxf((float)dg1, 1.0f));
        sb[w][0][lane] = agg0;
        sb[w][1][lane] = agg1;
        __builtin_amdgcn_wave_barrier();
        const float* h0 = hin + (size_t)n0 * 64;  // wave-uniform -> scalar loads
        const float* h1 = hin + (size_t)n1 * 64;
        float aL0 = bj, aR0 = 0.0f, aL1 = bj, aR1 = 0.0f;
#pragma unroll 8
        for (int k = 0; k < 64; ++k) {
            float wl = sWl[k * 64 + lane];
            float wr = sWr[k * 64 + lane];
            aL0 = fmaf(sb[w][0][k], wl, aL0);
            aR0 = fmaf(h0[k], wr, aR0);
            aL1 = fmaf(sb[w][1][k], wl, aL1);
            aR1 = fmaf(h1[k], wr, aR1);
        }
        __builtin_amdgcn_wave_barrier();
        hout[(size_t)n0 * 64 + lane] = fmaxf(aL0 + aR0, 0.0f);
        hout[(size_t)n1 * 64 + lane] = fmaxf(aL1 + aR1, 0.0f);
    }
}

// ---------------- pooling: batch sorted -> run-accumulate, flush on change ----
__global__ void __launch_bounds__(256) k_pool(const int* __restrict__ batch,
                                              const float* __restrict__ h,
                                              float* __restrict__ pool,
                                              float* __restrict__ cnt) {
    int lane = threadIdx.x & 63;
    int wid  = (blockIdx.x * 256 + threadIdx.x) >> 6;
    int nw   = (gridDim.x * 256) >> 6;
    int chunk = (NN + nw - 1) / nw;
    int n0 = wid * chunk;
    if (n0 >= NN) return;
    int n1 = min(n0 + chunk, NN);
    int cur = batch[n0];
    float acc = 0.0f, acc_c = 0.0f;
    for (int n = n0; n < n1; ++n) {
        int b = batch[n];
        if (b != cur) {
            atomicAdd(&pool[(size_t)cur * 64 + lane], acc);
            if (lane == 0) atomicAdd(&cnt[cur], acc_c);
            acc = 0.0f; acc_c = 0.0f; cur = b;
        }
        acc   += h[(size_t)n * 64 + lane];
        acc_c += 1.0f;
    }
    atomicAdd(&pool[(size_t)cur * 64 + lane], acc);
    if (lane == 0) atomicAdd(&cnt[cur], acc_c);
}

// ---------------- output GEMM: out = (pool/cnt) @ W1 + b1 ----------------
__global__ void __launch_bounds__(256) k_out(const float* __restrict__ pool,
                                             const float* __restrict__ cnt,
                                             const float* __restrict__ W1,
                                             const float* __restrict__ b1,
                                             float* __restrict__ out) {
    __shared__ float sW[64 * 64];
    for (int i = threadIdx.x; i < 64 * 64; i += 256) sW[i] = W1[i];
    __syncthreads();
    int lane = threadIdx.x & 63;
    int wid  = (blockIdx.x * 256 + threadIdx.x) >> 6;
    int nw   = (gridDim.x * 256) >> 6;
    for (int g = wid; g < NG; g += nw) {
        float ic = 1.0f / fmaxf(cnt[g], 1.0f);
        float acc = 0.0f;
#pragma unroll
        for (int k = 0; k < 64; ++k)
            acc = fmaf(pool[(size_t)g * 64 + k], sW[k * 64 + lane], acc);
        out[(size_t)g * 64 + lane] = fmaf(acc, ic, b1[lane]);
    }
}

extern "C" void kernel_launch(void* const* d_in, const int* in_sizes, int n_in,
                              void* d_out, int out_size, void* d_ws, size_t ws_size,
                              hipStream_t stream) {
    const float* x     = (const float*)d_in[0];
    const int*   ei    = (const int*)d_in[1];   // [2,E]: src = ei[0..E), dst = ei[E..2E)
    const int*   batch = (const int*)d_in[3];
    const float* W0    = (const float*)d_in[4];
    const float* b0    = (const float*)d_in[5];
    const float* Wl    = (const float*)d_in[6]; // [3,64,64]
    const float* bl    = (const float*)d_in[7]; // [3,64]
    const float* Wr    = (const float*)d_in[8]; // [3,64,64]
    const float* W1    = (const float*)d_in[9];
    const float* b1    = (const float*)d_in[10];
    float* out = (float*)d_out;

    char* ws = (char*)d_ws;
    size_t off = 0;
    auto alloc = [&](size_t bytes) -> void* {
        void* p = ws + off;
        off += (bytes + 255) & ~(size_t)255;
        return p;
    };
    float* A      = (float*)alloc((size_t)NN * 64 * 4);
    float* B      = (float*)alloc((size_t)NN * 64 * 4);
    int*   degi   = (int*)alloc((size_t)NN * 4);
    int*   rowptr = (int*)alloc((size_t)NN * 4);
    int*   cursor = (int*)alloc((size_t)NN * 4);
    int*   col    = (int*)alloc((size_t)NE * 4);
    float* pool   = (float*)alloc((size_t)NG * 64 * 4);  // pool & cnt contiguous
    float* cnt    = (float*)alloc((size_t)NG * 4);
    int*   bsum   = (int*)alloc((size_t)SCAN_NB * 4);

    const int* src = ei;
    const int* dst = ei + NE;

    // ---- CSR build ----
    hipMemsetAsync(degi, 0, (size_t)NN * 4, stream);
    k_deg<<<(NE / 4 + 255) / 256, 256, 0, stream>>>((const int4*)dst, degi);
    k_scan1<<<SCAN_NB, 1024, 0, stream>>>(degi, rowptr, bsum);
    k_scan2<<<SCAN_NB, 1024, 0, stream>>>(rowptr, cursor, bsum);
    k_fill<<<(NE / 4 + 255) / 256, 256, 0, stream>>>((const int4*)src, (const int4*)dst,
                                                     cursor, col);

    // ---- input projection ----
    k_in_gemm<<<1024, 512, 0, stream>>>(x, W0, b0, A);

    // ---- 3 fused SAGE layers ----
    for (int l = 0; l < 3; ++l) {
        k_sage<<<1024, 512, 0, stream>>>(A, B, rowptr, degi, col,
                                         Wl + (size_t)l * 64 * 64,
                                         bl + (size_t)l * 64,
                                         Wr + (size_t)l * 64 * 64);
        float* t = A; A = B; B = t;
    }

    // ---- global mean pool + output GEMM ----
    hipMemsetAsync(pool, 0, (size_t)NG * 64 * 4 + (size_t)NG * 4, stream);  // pool+cnt
    k_pool<<<256, 256, 0, stream>>>(batch, A, pool, cnt);
    k_out<<<128, 256, 0, stream>>>(pool, cnt, W1, b1, out);
}